// Round 11
// baseline (2403.028 us; speedup 1.0000x reference)
//
#include <hip/hip_runtime.h>
#include <math.h>

#define NN 100000
#define NE 1600000
#define DD 32
#define CC 16
#define SCAN_B 391  // ceil(NN/256)

typedef unsigned short bf16_t;
typedef __attribute__((ext_vector_type(8))) short short8v;
typedef __attribute__((ext_vector_type(4))) float float4v;
struct us4 { bf16_t x, y, z, w; };

static inline unsigned gblocks(long total) { return (unsigned)((total + 255) / 256); }

__device__ inline bf16_t f2bf(float f) {
    unsigned u = __float_as_uint(f);
    u += 0x7fffu + ((u >> 16) & 1u);
    return (bf16_t)(u >> 16);
}
__device__ inline float bf2f(bf16_t h) { return __uint_as_float(((unsigned)h) << 16); }
__device__ inline unsigned pk2(float a, float b) {
    return (unsigned)f2bf(a) | ((unsigned)f2bf(b) << 16);
}

__global__ void zero_int_k(int* p, int n) {
    int i = blockIdx.x * 256 + threadIdx.x;
    if (i < n) p[i] = 0;
}

// ---------------- CSR build (proven) ----------------
__global__ void hist_k(const int* __restrict__ dst, int* __restrict__ cnt) {
    int e = blockIdx.x * 256 + threadIdx.x;
    if (e < NE) atomicAdd(&cnt[dst[e]], 1);
}

__global__ void s1_k(const int* __restrict__ cnt, int* __restrict__ offs,
                     int* __restrict__ bsum) {
    __shared__ int sm[256];
    int t = threadIdx.x, b = blockIdx.x;
    int g = b * 256 + t;
    int v = (g < NN) ? cnt[g] : 0;
    sm[t] = v;
    __syncthreads();
    for (int o = 1; o < 256; o <<= 1) {
        int u = (t >= o) ? sm[t - o] : 0;
        __syncthreads();
        sm[t] += u;
        __syncthreads();
    }
    if (g < NN) offs[g + 1] = sm[t];
    if (t == 255) bsum[b] = sm[255];
}

__global__ void s2_k(int* __restrict__ bsum) {
    __shared__ int sm[512];
    int t = threadIdx.x;
    int v = (t < SCAN_B) ? bsum[t] : 0;
    sm[t] = v;
    __syncthreads();
    for (int o = 1; o < 512; o <<= 1) {
        int u = (t >= o) ? sm[t - o] : 0;
        __syncthreads();
        sm[t] += u;
        __syncthreads();
    }
    if (t < SCAN_B) bsum[t] = sm[t] - v;  // exclusive
}

__global__ void s3_k(int* __restrict__ offs, const int* __restrict__ bsum) {
    int t = threadIdx.x, b = blockIdx.x;
    int g = b * 256 + t;
    if (g < NN) offs[g + 1] += bsum[b];
    if (g == 0) offs[0] = 0;
}

__global__ void copyoff_k(const int* __restrict__ offs, int* __restrict__ cur) {
    int g = blockIdx.x * 256 + threadIdx.x;
    if (g < NN) cur[g] = offs[g];
}

// fill dst-sorted combined metadata stream: {src<<5|dst&31, attr quantized}
__global__ void fill_k(const int* __restrict__ dst, const int* __restrict__ src,
                       const float2* __restrict__ attr, int* __restrict__ cur,
                       uint2* __restrict__ emeta) {
    int e = blockIdx.x * 256 + threadIdx.x;
    if (e < NE) {
        int d = dst[e];
        int pos = atomicAdd(&cur[d], 1);
        float2 uv = attr[e];
        uint2 m;
        m.x = ((unsigned)src[e] << 5) | (unsigned)(d & 31);
        m.y = (unsigned)(uv.x * 65535.f + 0.5f) | ((unsigned)(uv.y * 65535.f + 0.5f) << 16);
        emeta[pos] = m;
    }
}

// f32 -> bf16 row cast (4 elems/thread)
__global__ void castxb_k(const float* __restrict__ in, bf16_t* __restrict__ outb) {
    long t = (long)blockIdx.x * 256 + threadIdx.x;
    if (t >= (long)NN * 8) return;
    float4 v = ((const float4*)in)[t];
    us4 o; o.x = f2bf(v.x); o.y = f2bf(v.y); o.z = f2bf(v.z); o.w = f2bf(v.w);
    ((us4*)outb)[t] = o;
}

// W[k in 0..K-1] + root (as slot K) -> B-fragment layout bf16:
// wtf[(k*2+half)*64 + l][r] = M[k][ 8*(l>>4)+r ][ (l&15)+16*half ]
__global__ void castw_k(const float* __restrict__ W, const float* __restrict__ root,
                        bf16_t* __restrict__ wtf, int K) {
    int tid = blockIdx.x * 256 + threadIdx.x;
    if (tid >= (K + 1) * 2 * 64) return;
    int l = tid & 63;
    int half = (tid >> 6) & 1;
    int k = tid >> 7;
    int e = (l & 15) + 16 * half;
    int dbase = (l >> 4) * 8;
    const float* M = (k < K) ? (W + (long)k * 1024) : root;
    bf16_t* op = wtf + (long)tid * 8;
#pragma unroll
    for (int r = 0; r < 8; ++r)
        op[r] = f2bf(M[(dbase + r) * DD + e]);
}

// ---------------- fully fused SplineConv layer ----------------
// Block = 16 dst nodes. Phase 1 (all 8 groups, unroll 4): for each in-edge,
// gather 64B bf16 x-row (L2-resident) and LDS-atomicAdd the 4 spline taps
// into z[n][k][d].  z[K] slot = x[n]*deg folds the root term.  Phase 2
// (2 waves): h[n][e] = (sum_k z@W)/deg + bias, ELU, via 16x16x32 bf16 MFMA
// (A=z fragments from LDS, B=wtf; mapping verified r8).
template<int KS>
__global__ __launch_bounds__(256) void layer_k(
        const int* __restrict__ offs, const uint2* __restrict__ emeta,
        const bf16_t* __restrict__ xb, const short8v* __restrict__ wtf,
        const float* __restrict__ bias, bf16_t* __restrict__ hout) {
    constexpr int K = KS * KS;
    constexpr int ZS = (K + 1) * 32 + 2;   // dword stride per node: %32==2 -> <=4-way banks
    __shared__ float zs[16 * ZS];
    __shared__ int offl[17];
    __shared__ float degl[16];

    const int tid = threadIdx.x;
    const int n0 = blockIdx.x * 16;
    if (tid < 17) offl[tid] = offs[n0 + tid];
    for (int i = tid; i < 16 * ZS; i += 256) zs[i] = 0.f;
    __syncthreads();

    const int lane = tid & 31, g = tid >> 5;
    if (tid < 16) degl[tid] = (float)max(offl[tid + 1] - offl[tid], 1);
    // z[K] = x[n] * deg (root term as extra k-slot); per-group own deg calc
    for (int ln = g; ln < 16; ln += 8) {
        float df = (float)max(offl[ln + 1] - offl[ln], 1);
        float xv = bf2f(xb[(long)(n0 + ln) * DD + lane]);
        zs[ln * ZS + K * 32 + lane] = xv * df;
    }

    const int j0 = offl[0], j1 = offl[16];
    const int b5 = n0 & 31;
    for (int jb = j0 + g * 4; jb < j1; jb += 32) {
        float w[4][4]; int ofs[4][4]; float xv[4];
#pragma unroll
        for (int i = 0; i < 4; ++i) {
            int jj = jb + i;
            bool val = jj < j1;
            if (!val) jj = j0;
            uint2 em = emeta[jj];          // sequential stream, broadcast
            int s = (int)(em.x >> 5);
            int dn = (int)(em.x & 31u) - b5;
            float u0 = (float)(em.y & 0xffffu) * (1.f / 65535.f);
            float u1 = (float)(em.y >> 16) * (1.f / 65535.f);
            float v0 = u0 * (KS - 1), v1 = u1 * (KS - 1);
            int i0 = (int)v0, i1 = (int)v1;
            float f0 = v0 - (float)i0, f1 = v1 - (float)i1;
            int q0 = min(i0 + 1, KS - 1), q1 = min(i1 + 1, KS - 1);
            float sv = val ? 1.f : 0.f;
            w[i][0] = (1.f - f0) * (1.f - f1) * sv;
            w[i][1] = f0 * (1.f - f1) * sv;
            w[i][2] = (1.f - f0) * f1 * sv;
            w[i][3] = f0 * f1 * sv;
            int zb = dn * ZS + lane;
            ofs[i][0] = zb + (i0 + i1 * KS) * 32;
            ofs[i][1] = zb + (q0 + i1 * KS) * 32;
            ofs[i][2] = zb + (i0 + q1 * KS) * 32;
            ofs[i][3] = zb + (q0 + q1 * KS) * 32;
            xv[i] = bf2f(xb[(long)s * DD + lane]);   // 64B coalesced gather, L2-hit
        }
#pragma unroll
        for (int i = 0; i < 4; ++i) {
#pragma unroll
            for (int t = 0; t < 4; ++t)
                atomicAdd(&zs[ofs[i][t]], w[i][t] * xv[i]);
        }
    }
    __syncthreads();

    // phase 2: contraction, waves 0 (e-half 0) and 1 (e-half 1)
    const int wid = tid >> 6;
    if (wid < 2) {
        const int l = tid & 63;
        const int nrow = l & 15, gq = l >> 4;
        const float* zrow = &zs[nrow * ZS + gq * 8];
        float4v acc = {0.f, 0.f, 0.f, 0.f};
        for (int t = 0; t <= K; ++t) {
            const float* zp = zrow + t * 32;
            float2 a0 = *(const float2*)(zp + 0);
            float2 a1 = *(const float2*)(zp + 2);
            float2 a2 = *(const float2*)(zp + 4);
            float2 a3 = *(const float2*)(zp + 6);
            uint4 au;
            au.x = pk2(a0.x, a0.y);
            au.y = pk2(a1.x, a1.y);
            au.z = pk2(a2.x, a2.y);
            au.w = pk2(a3.x, a3.y);
            short8v af = *(short8v*)&au;
            acc = __builtin_amdgcn_mfma_f32_16x16x32_bf16(af, wtf[(t * 2 + wid) * 64 + l], acc, 0, 0, 0);
        }
        int e = (l & 15) + 16 * wid;
        float bv = bias[e];
#pragma unroll
        for (int r = 0; r < 4; ++r) {
            int nr = (l >> 4) * 4 + r;       // D row = (lane>>4)*4 + reg (m89)
            float v = acc[r] / degl[nr] + bv;
            v = v > 0.f ? v : expm1f(v);
            hout[(long)(n0 + nr) * DD + e] = f2bf(v);
        }
    }
}

// fused 2-layer MLP head (bf16 input)
__global__ __launch_bounds__(256) void mlp_k(
        const bf16_t* __restrict__ h, const float* __restrict__ w1,
        const float* __restrict__ b1, const float* __restrict__ w2,
        const float* __restrict__ b2, float* __restrict__ out) {
    const int lane = threadIdx.x & 31;
    const int grp = threadIdx.x >> 5;
    const int n = blockIdx.x * 8 + grp;
    if (n >= NN) return;
    float hv = bf2f(h[(long)n * DD + lane]);
    float t = b1[lane];
#pragma unroll
    for (int d = 0; d < DD; ++d)
        t = fmaf(__shfl(hv, d, 32), w1[d * DD + lane], t);
    t = fmaxf(t, 0.f);
    int c = lane & (CC - 1);
    float o = 0.f;
#pragma unroll
    for (int d = 0; d < DD; ++d)
        o = fmaf(__shfl(t, d, 32), w2[d * CC + c], o);
    o += b2[c];
    o = fmaxf(o, 0.f);
    if (lane < CC) out[(long)n * CC + lane] = o;
}

extern "C" void kernel_launch(void* const* d_in, const int* in_sizes, int n_in,
                              void* d_out, int out_size, void* d_ws, size_t ws_size,
                              hipStream_t stream) {
    const float* x     = (const float*)d_in[0];
    const int*   ei    = (const int*)d_in[1];
    const float* attr  = (const float*)d_in[2];
    const float* W1    = (const float*)d_in[3];
    const float* root1 = (const float*)d_in[4];
    const float* bias1 = (const float*)d_in[5];
    const float* W2    = (const float*)d_in[6];
    const float* root2 = (const float*)d_in[7];
    const float* bias2 = (const float*)d_in[8];
    const float* m1w   = (const float*)d_in[9];
    const float* m1b   = (const float*)d_in[10];
    const float* m2w   = (const float*)d_in[11];
    const float* m2b   = (const float*)d_in[12];
    float* out = (float*)d_out;

    const int* srcp = ei;
    const int* dstp = ei + NE;

    // ws: offs(NN+8) | emeta(NE uint2) | xb | hb1 | hb2 (bf16 NN*32 each)
    //     | wtf1(10*2*64*8) | wtf2(26*2*64*8) | cur(NN) | bsum(512)   ~= 33.5 MB
    int* offs = (int*)d_ws;
    uint2* emeta = (uint2*)(offs + NN + 8);
    bf16_t* xb  = (bf16_t*)(emeta + NE);
    bf16_t* hb1 = xb + (size_t)NN * DD;
    bf16_t* hb2 = hb1 + (size_t)NN * DD;
    bf16_t* wtf1 = hb2 + (size_t)NN * DD;
    bf16_t* wtf2 = wtf1 + 10 * 2 * 64 * 8;
    int* cur  = (int*)(wtf2 + 26 * 2 * 64 * 8);
    int* bsum = cur + NN;

    const unsigned gn = (NN + 7) / 8;
    const unsigned gl = NN / 16;   // 6250 exact

    // ---- CSR build + packed metadata stream ----
    zero_int_k<<<gblocks(NN), 256, 0, stream>>>(cur, NN);
    hist_k<<<gblocks(NE), 256, 0, stream>>>(dstp, cur);
    s1_k<<<SCAN_B, 256, 0, stream>>>(cur, offs, bsum);
    s2_k<<<1, 512, 0, stream>>>(bsum);
    s3_k<<<SCAN_B, 256, 0, stream>>>(offs, bsum);
    copyoff_k<<<SCAN_B, 256, 0, stream>>>(offs, cur);
    fill_k<<<gblocks(NE), 256, 0, stream>>>(dstp, srcp, (const float2*)attr, cur, emeta);

    // ---- weight fragment packs (W + root as slot K) ----
    castw_k<<<gblocks(10 * 2 * 64), 256, 0, stream>>>(W1, root1, wtf1, 9);
    castw_k<<<gblocks(26 * 2 * 64), 256, 0, stream>>>(W2, root2, wtf2, 25);

    // ---- input cast ----
    castxb_k<<<gblocks((long)NN * 8), 256, 0, stream>>>(x, xb);

    // ---- fused layers ----
    layer_k<3><<<gl, 256, 0, stream>>>(offs, emeta, xb, (const short8v*)wtf1, bias1, hb1);
    layer_k<5><<<gl, 256, 0, stream>>>(offs, emeta, hb1, (const short8v*)wtf2, bias2, hb2);

    // ---- fused MLP head ----
    mlp_k<<<gn, 256, 0, stream>>>(hb2, m1w, m1b, m2w, m2b, out);
}

// Round 12
// 711.285 us; speedup vs baseline: 3.3784x; 3.3784x over previous
//
#include <hip/hip_runtime.h>
#include <math.h>

#define NN 100000
#define NE 1600000
#define DD 32
#define CC 16
#define SCAN_B 391   // ceil(NN/256)
#define NB (NE / 8)  // 200000 edge blocks, exact

typedef unsigned short bf16_t;
typedef __attribute__((ext_vector_type(8))) short short8v;
typedef __attribute__((ext_vector_type(4))) float float4v;

static inline unsigned gblocks(long total) { return (unsigned)((total + 255) / 256); }

__device__ inline bf16_t f2bf(float f) {
    unsigned u = __float_as_uint(f);
    u += 0x7fffu + ((u >> 16) & 1u);
    return (bf16_t)(u >> 16);
}
__device__ inline float bf2f(bf16_t h) { return __uint_as_float(((unsigned)h) << 16); }
__device__ inline unsigned pk2(float a, float b) {
    return (unsigned)f2bf(a) | ((unsigned)f2bf(b) << 16);
}

__global__ void zero_k(float* p, long n) {
    long i = (long)blockIdx.x * 256 + threadIdx.x;
    if (i < n) p[i] = 0.f;
}
__global__ void zero_int_k(int* p, int n) {
    int i = blockIdx.x * 256 + threadIdx.x;
    if (i < n) p[i] = 0;
}

// ---------------- CSR build (proven) ----------------
__global__ void hist_k(const int* __restrict__ dst, int* __restrict__ cnt) {
    int e = blockIdx.x * 256 + threadIdx.x;
    if (e < NE) atomicAdd(&cnt[dst[e]], 1);
}
__global__ void s1_k(const int* __restrict__ cnt, int* __restrict__ offs,
                     int* __restrict__ bsum) {
    __shared__ int sm[256];
    int t = threadIdx.x, b = blockIdx.x;
    int g = b * 256 + t;
    int v = (g < NN) ? cnt[g] : 0;
    sm[t] = v;
    __syncthreads();
    for (int o = 1; o < 256; o <<= 1) {
        int u = (t >= o) ? sm[t - o] : 0;
        __syncthreads();
        sm[t] += u;
        __syncthreads();
    }
    if (g < NN) offs[g + 1] = sm[t];
    if (t == 255) bsum[b] = sm[255];
}
__global__ void s2_k(int* __restrict__ bsum) {
    __shared__ int sm[512];
    int t = threadIdx.x;
    int v = (t < SCAN_B) ? bsum[t] : 0;
    sm[t] = v;
    __syncthreads();
    for (int o = 1; o < 512; o <<= 1) {
        int u = (t >= o) ? sm[t - o] : 0;
        __syncthreads();
        sm[t] += u;
        __syncthreads();
    }
    if (t < SCAN_B) bsum[t] = sm[t] - v;  // exclusive
}
__global__ void s3_k(int* __restrict__ offs, const int* __restrict__ bsum) {
    int t = threadIdx.x, b = blockIdx.x;
    int g = b * 256 + t;
    if (g < NN) offs[g + 1] += bsum[b];
    if (g == 0) offs[0] = 0;
}
__global__ void copyoff_k(const int* __restrict__ offs, int* __restrict__ cur) {
    int g = blockIdx.x * 256 + threadIdx.x;
    if (g < NN) cur[g] = offs[g];
}

// fill dst-sorted stream: emeta[j] = {src, attr 2x16b fixed-point}
__global__ void fill_k(const int* __restrict__ dst, const int* __restrict__ src,
                       const float2* __restrict__ attr, int* __restrict__ cur,
                       uint2* __restrict__ emeta) {
    int e = blockIdx.x * 256 + threadIdx.x;
    if (e < NE) {
        int d = dst[e];
        int pos = atomicAdd(&cur[d], 1);
        float2 uv = attr[e];
        uint2 m;
        m.x = (unsigned)src[e];
        m.y = (unsigned)(uv.x * 65535.f + 0.5f) | ((unsigned)(uv.y * 65535.f + 0.5f) << 16);
        emeta[pos] = m;
    }
}

// per edge-block b: dst node of edge 8b via binary search (one-time)
__global__ void dstbase_k(const int* __restrict__ offs, int* __restrict__ dstbase) {
    int b = blockIdx.x * 256 + threadIdx.x;
    if (b >= NB) return;
    int j = b * 8;
    int lo = 0, hi = NN - 1;
    while (lo < hi) {
        int mid = (lo + hi + 1) >> 1;
        if (offs[mid] <= j) lo = mid; else hi = mid - 1;
    }
    dstbase[b] = lo;
}

// ---------------- MFMA y pipeline (proven r8) ----------------
__global__ void castx_k(const float* __restrict__ in, bf16_t* __restrict__ outf) {
    int tid = blockIdx.x * 256 + threadIdx.x;  // (n, q)
    if (tid >= NN * 4) return;
    int n = tid >> 2, q = tid & 3;
    const float4* ip = (const float4*)(in + (long)n * DD + q * 8);
    float4 v0 = ip[0], v1 = ip[1];
    int tile = n >> 4;
    int lane = (n & 15) + 16 * q;
    unsigned* op = (unsigned*)(outf + ((long)tile * 64 + lane) * 8);
    op[0] = pk2(v0.x, v0.y);
    op[1] = pk2(v0.z, v0.w);
    op[2] = pk2(v1.x, v1.y);
    op[3] = pk2(v1.z, v1.w);
}

__global__ void castw_k(const float* __restrict__ W, bf16_t* __restrict__ wtf, int K) {
    int tid = blockIdx.x * 256 + threadIdx.x;
    if (tid >= K * 2 * 64) return;
    int l = tid & 63;
    int half = (tid >> 6) & 1;
    int k = tid >> 7;
    int e = (l & 15) + 16 * half;
    int dbase = (l >> 4) * 8;
    bf16_t* op = wtf + (long)tid * 8;
#pragma unroll
    for (int r = 0; r < 8; ++r)
        op[r] = f2bf(W[(long)k * 1024 + (dbase + r) * DD + e]);
}

template<int K>
__global__ __launch_bounds__(64) void ymm_k(const short8v* __restrict__ xtf,
                                            const short8v* __restrict__ wtf,
                                            unsigned* __restrict__ y) {
    constexpr int RS = K * 16 + 4;
    __shared__ unsigned lds[16 * RS];
    const int l = threadIdx.x;
    const int tile = blockIdx.x;
    const int node = l & 15, g = l >> 4;

    short8v b = xtf[(long)tile * 64 + l];
    float4v zz = {0.f, 0.f, 0.f, 0.f};

    for (int k = 0; k < K; ++k) {
        float4v d0 = __builtin_amdgcn_mfma_f32_16x16x32_bf16(wtf[(2 * k + 0) * 64 + l], b, zz, 0, 0, 0);
        float4v d1 = __builtin_amdgcn_mfma_f32_16x16x32_bf16(wtf[(2 * k + 1) * 64 + l], b, zz, 0, 0, 0);
        unsigned* lr = &lds[node * RS + k * 16];
        lr[2 * g]     = pk2(d0[0], d0[1]);
        lr[2 * g + 1] = pk2(d0[2], d0[3]);
        lr[8 + 2 * g]     = pk2(d1[0], d1[1]);
        lr[8 + 2 * g + 1] = pk2(d1[2], d1[3]);
    }
    __syncthreads();

    unsigned* yb = y + (long)tile * (16 * K * 16);
    constexpr int TOT = 16 * K * 16;
    for (int off = l * 4; off < TOT; off += 256) {
        int nd = off / (K * 16);
        int rem = off - nd * (K * 16);
        const unsigned* lp = &lds[nd * RS + rem];
        uint4 v = make_uint4(lp[0], lp[1], lp[2], lp[3]);
        *(uint4*)(yb + off) = v;
    }
}

// ---------------- sorted edge phase with block-segmented reduce ----------------
// Block = 8 consecutive sorted edges, one per 32-lane group (NO serial loops).
// dst recovered from dstbase[b] + short offs walk. Messages staged in LDS;
// run-leader groups flush one atomic per (run, dim) -> atomics / ~5.
template<int KS>
__global__ __launch_bounds__(256) void edge_sr_k(
        const int* __restrict__ offs, const int* __restrict__ dstbase,
        const uint2* __restrict__ emeta, const bf16_t* __restrict__ y,
        float* __restrict__ agg) {
    constexpr int K = KS * KS;
    __shared__ float sm[8][33];
    __shared__ int sdst[8];
    const int tid = threadIdx.x;
    const int lane = tid & 31, g = tid >> 5;
    const int b = blockIdx.x;
    const int j = b * 8 + g;

    uint2 em = emeta[j];
    int n = dstbase[b];
    while (offs[n + 1] <= j) ++n;   // group-uniform short walk (L1/L2-hot)

    int s = (int)em.x;
    float u0 = (float)(em.y & 0xffffu) * (1.f / 65535.f);
    float u1 = (float)(em.y >> 16) * (1.f / 65535.f);
    float v0 = u0 * (KS - 1), v1 = u1 * (KS - 1);
    int i0 = min((int)v0, KS - 1), i1 = min((int)v1, KS - 1);
    float f0 = v0 - (float)i0, f1 = v1 - (float)i1;
    int q0 = min(i0 + 1, KS - 1), q1 = min(i1 + 1, KS - 1);
    const bf16_t* yb = y + (long)s * (K * DD) + lane;
    float y00 = bf2f(yb[(i0 + i1 * KS) * DD]);
    float y10 = bf2f(yb[(q0 + i1 * KS) * DD]);
    float y01 = bf2f(yb[(i0 + q1 * KS) * DD]);
    float y11 = bf2f(yb[(q0 + q1 * KS) * DD]);
    float m = (1.f - f0) * (1.f - f1) * y00 + f0 * (1.f - f1) * y10
            + (1.f - f0) * f1 * y01 + f0 * f1 * y11;

    sm[g][lane] = m;
    if (lane == 0) sdst[g] = n;
    __syncthreads();

    // run leaders flush
    bool leader = (g == 0) || (sdst[g - 1] != n);
    if (leader) {
        float acc = sm[g][lane];
#pragma unroll
        for (int gg = 1; gg < 8; ++gg) {
            int g2 = g + gg;
            if (g2 >= 8 || sdst[g2] != n) break;
            acc += sm[g2][lane];
        }
        atomicAdd(&agg[(long)n * DD + lane], acc);
    }
}

// finalize layer 1: h1 = elu(agg/deg + x@root + bias), written as bf16 MFMA
// B-fragments directly into xtf (kills the separate castx pass for layer 2)
__global__ __launch_bounds__(256) void fin1_k(
        const float* __restrict__ agg, const int* __restrict__ offs,
        const float* __restrict__ xin, const float* __restrict__ root,
        const float* __restrict__ bias, bf16_t* __restrict__ xtf) {
    const int lane = threadIdx.x & 31;
    const int grp = threadIdx.x >> 5;
    const int n = blockIdx.x * 8 + grp;
    if (n >= NN) return;
    int deg = offs[n + 1] - offs[n];
    float c = deg > 0 ? (float)deg : 1.f;
    float xv = xin[(long)n * DD + lane];
    float racc = 0.f;
#pragma unroll
    for (int d = 0; d < DD; ++d)
        racc = fmaf(__shfl(xv, d, 32), root[d * DD + lane], racc);
    float v = agg[(long)n * DD + lane] / c + racc + bias[lane];
    v = v > 0.f ? v : expm1f(v);
    // fragment slot: tile=n>>4, frag=(n&15)+16*(d>>3), reg=d&7  (d = lane)
    xtf[((long)(n >> 4) * 64 + (n & 15) + 16 * (lane >> 3)) * 8 + (lane & 7)] = f2bf(v);
}

// finalize layer 2 in place: agg := elu(agg/deg + h1@root + bias); h1 read
// from the bf16 fragment buffer
__global__ __launch_bounds__(256) void fin2_k(
        float* __restrict__ agg, const int* __restrict__ offs,
        const bf16_t* __restrict__ xtf, const float* __restrict__ root,
        const float* __restrict__ bias) {
    const int lane = threadIdx.x & 31;
    const int grp = threadIdx.x >> 5;
    const int n = blockIdx.x * 8 + grp;
    if (n >= NN) return;
    int deg = offs[n + 1] - offs[n];
    float c = deg > 0 ? (float)deg : 1.f;
    float xv = bf2f(xtf[((long)(n >> 4) * 64 + (n & 15) + 16 * (lane >> 3)) * 8 + (lane & 7)]);
    float racc = 0.f;
#pragma unroll
    for (int d = 0; d < DD; ++d)
        racc = fmaf(__shfl(xv, d, 32), root[d * DD + lane], racc);
    float v = agg[(long)n * DD + lane] / c + racc + bias[lane];
    agg[(long)n * DD + lane] = v > 0.f ? v : expm1f(v);
}

// fused 2-layer MLP head (f32 input)
__global__ __launch_bounds__(256) void mlp_k(
        const float* __restrict__ h, const float* __restrict__ w1,
        const float* __restrict__ b1, const float* __restrict__ w2,
        const float* __restrict__ b2, float* __restrict__ out) {
    const int lane = threadIdx.x & 31;
    const int grp = threadIdx.x >> 5;
    const int n = blockIdx.x * 8 + grp;
    if (n >= NN) return;
    float hv = h[(long)n * DD + lane];
    float t = b1[lane];
#pragma unroll
    for (int d = 0; d < DD; ++d)
        t = fmaf(__shfl(hv, d, 32), w1[d * DD + lane], t);
    t = fmaxf(t, 0.f);
    int c = lane & (CC - 1);
    float o = 0.f;
#pragma unroll
    for (int d = 0; d < DD; ++d)
        o = fmaf(__shfl(t, d, 32), w2[d * CC + c], o);
    o += b2[c];
    o = fmaxf(o, 0.f);
    if (lane < CC) out[(long)n * CC + lane] = o;
}

extern "C" void kernel_launch(void* const* d_in, const int* in_sizes, int n_in,
                              void* d_out, int out_size, void* d_ws, size_t ws_size,
                              hipStream_t stream) {
    const float* x     = (const float*)d_in[0];
    const int*   ei    = (const int*)d_in[1];
    const float* attr  = (const float*)d_in[2];
    const float* W1    = (const float*)d_in[3];
    const float* root1 = (const float*)d_in[4];
    const float* bias1 = (const float*)d_in[5];
    const float* W2    = (const float*)d_in[6];
    const float* root2 = (const float*)d_in[7];
    const float* bias2 = (const float*)d_in[8];
    const float* m1w   = (const float*)d_in[9];
    const float* m1b   = (const float*)d_in[10];
    const float* m2w   = (const float*)d_in[11];
    const float* m2b   = (const float*)d_in[12];
    float* out = (float*)d_out;

    const int* srcp = ei;
    const int* dstp = ei + NE;

    // ws: offs(NN+8) | dstbase(NB) | emeta(NE uint2) | xtf(NN*32 bf16)
    //     | wtf1 | wtf2 | y(NN*25*32 bf16) | agg(NN*32 f32)
    // cur/bsum alias agg during CSR phase.  total ~193.3 MB
    int* offs = (int*)d_ws;
    int* dstbase = offs + NN + 8;
    uint2* emeta = (uint2*)(dstbase + NB);
    bf16_t* xtf = (bf16_t*)(emeta + NE);
    bf16_t* wtf1 = xtf + (size_t)NN * DD;
    bf16_t* wtf2 = wtf1 + 9 * 2 * 64 * 8;
    bf16_t* y = wtf2 + 25 * 2 * 64 * 8;
    float* agg = (float*)(y + (size_t)NN * 25 * DD);
    int* cur  = (int*)agg;
    int* bsum = (int*)agg + NN;

    const unsigned gn = (NN + 7) / 8;
    const unsigned gt = NN / 16;   // 6250 exact

    // ---- CSR build + sorted metadata stream ----
    zero_int_k<<<gblocks(NN), 256, 0, stream>>>(cur, NN);
    hist_k<<<gblocks(NE), 256, 0, stream>>>(dstp, cur);
    s1_k<<<SCAN_B, 256, 0, stream>>>(cur, offs, bsum);
    s2_k<<<1, 512, 0, stream>>>(bsum);
    s3_k<<<SCAN_B, 256, 0, stream>>>(offs, bsum);
    copyoff_k<<<SCAN_B, 256, 0, stream>>>(offs, cur);
    fill_k<<<gblocks(NE), 256, 0, stream>>>(dstp, srcp, (const float2*)attr, cur, emeta);
    dstbase_k<<<gblocks(NB), 256, 0, stream>>>(offs, dstbase);

    // ---- weight fragment packs ----
    castw_k<<<gblocks(9 * 2 * 64), 256, 0, stream>>>(W1, wtf1, 9);
    castw_k<<<gblocks(25 * 2 * 64), 256, 0, stream>>>(W2, wtf2, 25);

    // ---- layer 1 (ksize=3, K=9) ----
    castx_k<<<gblocks(NN * 4), 256, 0, stream>>>(x, xtf);
    ymm_k<9><<<gt, 64, 0, stream>>>((const short8v*)xtf, (const short8v*)wtf1, (unsigned*)y);
    zero_k<<<gblocks((long)NN * DD), 256, 0, stream>>>(agg, (long)NN * DD);
    edge_sr_k<3><<<NB, 256, 0, stream>>>(offs, dstbase, emeta, y, agg);
    fin1_k<<<gn, 256, 0, stream>>>(agg, offs, x, root1, bias1, xtf);  // h1 -> fragments

    // ---- layer 2 (ksize=5, K=25) ----
    ymm_k<25><<<gt, 64, 0, stream>>>((const short8v*)xtf, (const short8v*)wtf2, (unsigned*)y);
    zero_k<<<gblocks((long)NN * DD), 256, 0, stream>>>(agg, (long)NN * DD);
    edge_sr_k<5><<<NB, 256, 0, stream>>>(offs, dstbase, emeta, y, agg);
    fin2_k<<<gn, 256, 0, stream>>>(agg, offs, xtf, root2, bias2);     // agg := h2

    // ---- fused MLP head ----
    mlp_k<<<gn, 256, 0, stream>>>(agg, m1w, m1b, m2w, m2b, out);
}

// Round 13
// 670.378 us; speedup vs baseline: 3.5846x; 1.0610x over previous
//
#include <hip/hip_runtime.h>
#include <math.h>

#define NN 100000
#define NE 1600000
#define DD 32
#define CC 16
#define SCAN_B 391   // ceil(NN/256)
#define NB (NE / 8)  // 200000 edge blocks, exact

typedef unsigned short bf16_t;
typedef __attribute__((ext_vector_type(8))) short short8v;
typedef __attribute__((ext_vector_type(4))) float float4v;

static inline unsigned gblocks(long total) { return (unsigned)((total + 255) / 256); }

__device__ inline bf16_t f2bf(float f) {
    unsigned u = __float_as_uint(f);
    u += 0x7fffu + ((u >> 16) & 1u);
    return (bf16_t)(u >> 16);
}
__device__ inline float bf2f(bf16_t h) { return __uint_as_float(((unsigned)h) << 16); }
__device__ inline unsigned pk2(float a, float b) {
    return (unsigned)f2bf(a) | ((unsigned)f2bf(b) << 16);
}

__global__ void zero_k(float* p, long n) {
    long i = (long)blockIdx.x * 256 + threadIdx.x;
    if (i < n) p[i] = 0.f;
}
__global__ void zero_int_k(int* p, int n) {
    int i = blockIdx.x * 256 + threadIdx.x;
    if (i < n) p[i] = 0;
}

// ---------------- CSR build (proven) ----------------
__global__ void hist_k(const int* __restrict__ dst, int* __restrict__ cnt) {
    int e = blockIdx.x * 256 + threadIdx.x;
    if (e < NE) atomicAdd(&cnt[dst[e]], 1);
}
__global__ void s1_k(const int* __restrict__ cnt, int* __restrict__ offs,
                     int* __restrict__ bsum) {
    __shared__ int sm[256];
    int t = threadIdx.x, b = blockIdx.x;
    int g = b * 256 + t;
    int v = (g < NN) ? cnt[g] : 0;
    sm[t] = v;
    __syncthreads();
    for (int o = 1; o < 256; o <<= 1) {
        int u = (t >= o) ? sm[t - o] : 0;
        __syncthreads();
        sm[t] += u;
        __syncthreads();
    }
    if (g < NN) offs[g + 1] = sm[t];
    if (t == 255) bsum[b] = sm[255];
}
__global__ void s2_k(int* __restrict__ bsum) {
    __shared__ int sm[512];
    int t = threadIdx.x;
    int v = (t < SCAN_B) ? bsum[t] : 0;
    sm[t] = v;
    __syncthreads();
    for (int o = 1; o < 512; o <<= 1) {
        int u = (t >= o) ? sm[t - o] : 0;
        __syncthreads();
        sm[t] += u;
        __syncthreads();
    }
    if (t < SCAN_B) bsum[t] = sm[t] - v;  // exclusive
}
__global__ void s3_k(int* __restrict__ offs, const int* __restrict__ bsum) {
    int t = threadIdx.x, b = blockIdx.x;
    int g = b * 256 + t;
    if (g < NN) offs[g + 1] += bsum[b];
    if (g == 0) offs[0] = 0;
}
__global__ void copyoff_k(const int* __restrict__ offs, int* __restrict__ cur) {
    int g = blockIdx.x * 256 + threadIdx.x;
    if (g < NN) cur[g] = offs[g];
}

// fill dst-sorted stream: emeta[j] = {src, attr 2x16b fixed-point}
__global__ void fill_k(const int* __restrict__ dst, const int* __restrict__ src,
                       const float2* __restrict__ attr, int* __restrict__ cur,
                       uint2* __restrict__ emeta) {
    int e = blockIdx.x * 256 + threadIdx.x;
    if (e < NE) {
        int d = dst[e];
        int pos = atomicAdd(&cur[d], 1);
        float2 uv = attr[e];
        uint2 m;
        m.x = (unsigned)src[e];
        m.y = (unsigned)(uv.x * 65535.f + 0.5f) | ((unsigned)(uv.y * 65535.f + 0.5f) << 16);
        emeta[pos] = m;
    }
}

// per edge-block b: dst node of edge 8b via binary search (one-time)
__global__ void dstbase_k(const int* __restrict__ offs, int* __restrict__ dstbase) {
    int b = blockIdx.x * 256 + threadIdx.x;
    if (b >= NB) return;
    int j = b * 8;
    int lo = 0, hi = NN - 1;
    while (lo < hi) {
        int mid = (lo + hi + 1) >> 1;
        if (offs[mid] <= j) lo = mid; else hi = mid - 1;
    }
    dstbase[b] = lo;
}

// ---------------- MFMA y pipeline ----------------
__global__ void castx_k(const float* __restrict__ in, bf16_t* __restrict__ outf) {
    int tid = blockIdx.x * 256 + threadIdx.x;  // (n, q)
    if (tid >= NN * 4) return;
    int n = tid >> 2, q = tid & 3;
    const float4* ip = (const float4*)(in + (long)n * DD + q * 8);
    float4 v0 = ip[0], v1 = ip[1];
    int tile = n >> 4;
    int lane = (n & 15) + 16 * q;
    unsigned* op = (unsigned*)(outf + ((long)tile * 64 + lane) * 8);
    op[0] = pk2(v0.x, v0.y);
    op[1] = pk2(v0.z, v0.w);
    op[2] = pk2(v1.x, v1.y);
    op[3] = pk2(v1.z, v1.w);
}

__global__ void castw_k(const float* __restrict__ W, bf16_t* __restrict__ wtf, int K) {
    int tid = blockIdx.x * 256 + threadIdx.x;
    if (tid >= K * 2 * 64) return;
    int l = tid & 63;
    int half = (tid >> 6) & 1;
    int k = tid >> 7;
    int e = (l & 15) + 16 * half;
    int dbase = (l >> 4) * 8;
    bf16_t* op = wtf + (long)tid * 8;
#pragma unroll
    for (int r = 0; r < 8; ++r)
        op[r] = f2bf(W[(long)k * 1024 + (dbase + r) * DD + e]);
}

// y[n][k][d] = x[n,:] @ W[k].  Direct register->global stores (no LDS):
// partial-line stores are safe (byte-dirty L2 tracking, r2 vs r7 evidence).
// D-map (m89): col=lane&15 -> node, row=(lane>>4)*4+reg -> e within half.
template<int K>
__global__ __launch_bounds__(64) void ymm_k(const short8v* __restrict__ xtf,
                                            const short8v* __restrict__ wtf,
                                            uint2* __restrict__ y) {
    const int l = threadIdx.x;
    const int tile = blockIdx.x;
    const int node = l & 15, g = l >> 4;

    short8v b = xtf[(long)tile * 64 + l];
    float4v zz = {0.f, 0.f, 0.f, 0.f};
    const long nb = ((long)tile * 16 + node) * K;  // row index base

    for (int k = 0; k < K; ++k) {
        float4v d0 = __builtin_amdgcn_mfma_f32_16x16x32_bf16(wtf[(2 * k + 0) * 64 + l], b, zz, 0, 0, 0);
        float4v d1 = __builtin_amdgcn_mfma_f32_16x16x32_bf16(wtf[(2 * k + 1) * 64 + l], b, zz, 0, 0, 0);
        uint2 s0, s1;
        s0.x = pk2(d0[0], d0[1]); s0.y = pk2(d0[2], d0[3]);
        s1.x = pk2(d1[0], d1[1]); s1.y = pk2(d1[2], d1[3]);
        y[(nb + k) * 8 + g] = s0;        // e = g*4 .. g*4+3
        y[(nb + k) * 8 + 4 + g] = s1;    // e = 16 + g*4 ..
    }
}

// ---------------- sorted edge phase: pair-loads + segmented reduce ----------------
// Per edge (one 32-lane group): clamp i0,i1 to [0,KS-2], f=v-i; the 2x2 tap
// patch = rows (i0,i0+1) at planes (i1,i1+1) -- always in-bounds.  Two fully
// coalesced 128B loads (rows adjacent); shfl_xor(16) combines the row pair.
template<int KS>
__global__ __launch_bounds__(256) void edge_sr_k(
        const int* __restrict__ offs, const int* __restrict__ dstbase,
        const uint2* __restrict__ emeta, const unsigned* __restrict__ yu,
        float* __restrict__ agg) {
    constexpr int K = KS * KS;
    __shared__ float smf[8][36];
    __shared__ int sdst[8];
    const int tid = threadIdx.x;
    const int lane = tid & 31, g = tid >> 5;
    const int al = lane & 15, half = lane >> 4;
    const int b = blockIdx.x;
    const int j = b * 8 + g;

    uint2 em = emeta[j];
    int n = dstbase[b];
    while (offs[n + 1] <= j) ++n;   // group-uniform short walk

    int s = (int)em.x;
    float u0 = (float)(em.y & 0xffffu) * (1.f / 65535.f);
    float u1 = (float)(em.y >> 16) * (1.f / 65535.f);
    float v0 = u0 * (KS - 1), v1 = u1 * (KS - 1);
    int i0 = min((int)v0, KS - 2), i1 = min((int)v1, KS - 2);
    float f0 = v0 - (float)i0, f1 = v1 - (float)i1;

    float wh = half ? f0 : (1.f - f0);
    long base = ((long)s * K + i1 * KS + i0 + half) * 16 + al;
    unsigned uA = yu[base];             // plane i1, row (i0+half), dims 2al,2al+1
    unsigned uB = yu[base + KS * 16];   // plane i1+1
    float wA = wh * (1.f - f1), wB = wh * f1;
    float p0 = wA * bf2f((bf16_t)(uA & 0xffffu)) + wB * bf2f((bf16_t)(uB & 0xffffu));
    float p1 = wA * bf2f((bf16_t)(uA >> 16)) + wB * bf2f((bf16_t)(uB >> 16));
    p0 += __shfl_xor(p0, 16);   // combine row i0 with row i0+1
    p1 += __shfl_xor(p1, 16);

    if (half == 0) {
        smf[g][2 * al] = p0;
        smf[g][2 * al + 1] = p1;
    }
    if (lane == 0) sdst[g] = n;
    __syncthreads();

    bool leader = (g == 0) || (sdst[g - 1] != n);
    if (leader) {
        float acc = smf[g][lane];
#pragma unroll
        for (int gg = 1; gg < 8; ++gg) {
            int g2 = g + gg;
            if (g2 >= 8 || sdst[g2] != n) break;
            acc += smf[g2][lane];
        }
        atomicAdd(&agg[(long)n * DD + lane], acc);
    }
}

// finalize layer 1: h1 = elu(agg/deg + x@root + bias) -> bf16 fragments in xtf;
// also re-zeroes agg for layer 2 (replaces a zero_k pass).
__global__ __launch_bounds__(256) void fin1_k(
        float* __restrict__ agg, const int* __restrict__ offs,
        const float* __restrict__ xin, const float* __restrict__ root,
        const float* __restrict__ bias, bf16_t* __restrict__ xtf) {
    const int lane = threadIdx.x & 31;
    const int grp = threadIdx.x >> 5;
    const int n = blockIdx.x * 8 + grp;
    if (n >= NN) return;
    int deg = offs[n + 1] - offs[n];
    float c = deg > 0 ? (float)deg : 1.f;
    float xv = xin[(long)n * DD + lane];
    float racc = 0.f;
#pragma unroll
    for (int d = 0; d < DD; ++d)
        racc = fmaf(__shfl(xv, d, 32), root[d * DD + lane], racc);
    float v = agg[(long)n * DD + lane] / c + racc + bias[lane];
    agg[(long)n * DD + lane] = 0.f;   // ready for layer 2
    v = v > 0.f ? v : expm1f(v);
    xtf[((long)(n >> 4) * 64 + (n & 15) + 16 * (lane >> 3)) * 8 + (lane & 7)] = f2bf(v);
}

// fused: layer-2 finalize + 2-layer MLP head -> out
__global__ __launch_bounds__(256) void finmlp_k(
        const float* __restrict__ agg, const int* __restrict__ offs,
        const bf16_t* __restrict__ xtf, const float* __restrict__ root,
        const float* __restrict__ bias, const float* __restrict__ w1,
        const float* __restrict__ b1, const float* __restrict__ w2,
        const float* __restrict__ b2, float* __restrict__ out) {
    const int lane = threadIdx.x & 31;
    const int grp = threadIdx.x >> 5;
    const int n = blockIdx.x * 8 + grp;
    if (n >= NN) return;
    int deg = offs[n + 1] - offs[n];
    float c = deg > 0 ? (float)deg : 1.f;
    float h1 = bf2f(xtf[((long)(n >> 4) * 64 + (n & 15) + 16 * (lane >> 3)) * 8 + (lane & 7)]);
    float racc = 0.f;
#pragma unroll
    for (int d = 0; d < DD; ++d)
        racc = fmaf(__shfl(h1, d, 32), root[d * DD + lane], racc);
    float h2 = agg[(long)n * DD + lane] / c + racc + bias[lane];
    h2 = h2 > 0.f ? h2 : expm1f(h2);
    float t = b1[lane];
#pragma unroll
    for (int d = 0; d < DD; ++d)
        t = fmaf(__shfl(h2, d, 32), w1[d * DD + lane], t);
    t = fmaxf(t, 0.f);
    int cc = lane & (CC - 1);
    float o = 0.f;
#pragma unroll
    for (int d = 0; d < DD; ++d)
        o = fmaf(__shfl(t, d, 32), w2[d * CC + cc], o);
    o += b2[cc];
    o = fmaxf(o, 0.f);
    if (lane < CC) out[(long)n * CC + lane] = o;
}

extern "C" void kernel_launch(void* const* d_in, const int* in_sizes, int n_in,
                              void* d_out, int out_size, void* d_ws, size_t ws_size,
                              hipStream_t stream) {
    const float* x     = (const float*)d_in[0];
    const int*   ei    = (const int*)d_in[1];
    const float* attr  = (const float*)d_in[2];
    const float* W1    = (const float*)d_in[3];
    const float* root1 = (const float*)d_in[4];
    const float* bias1 = (const float*)d_in[5];
    const float* W2    = (const float*)d_in[6];
    const float* root2 = (const float*)d_in[7];
    const float* bias2 = (const float*)d_in[8];
    const float* m1w   = (const float*)d_in[9];
    const float* m1b   = (const float*)d_in[10];
    const float* m2w   = (const float*)d_in[11];
    const float* m2b   = (const float*)d_in[12];
    float* out = (float*)d_out;

    const int* srcp = ei;
    const int* dstp = ei + NE;

    // ws: offs(NN+8) | dstbase(NB) | emeta(NE uint2) | xtf(NN*32 bf16)
    //     | wtf1 | wtf2 | y(NN*25*32 bf16) | agg(NN*32 f32)  ~193.3 MB
    // cur/bsum alias agg during the CSR phase (agg zeroed after fill).
    int* offs = (int*)d_ws;
    int* dstbase = offs + NN + 8;
    uint2* emeta = (uint2*)(dstbase + NB);
    bf16_t* xtf = (bf16_t*)(emeta + NE);
    bf16_t* wtf1 = xtf + (size_t)NN * DD;
    bf16_t* wtf2 = wtf1 + 9 * 2 * 64 * 8;
    bf16_t* y = wtf2 + 25 * 2 * 64 * 8;
    float* agg = (float*)(y + (size_t)NN * 25 * DD);
    int* cur  = (int*)agg;
    int* bsum = (int*)agg + NN;

    const unsigned gn = (NN + 7) / 8;
    const unsigned gt = NN / 16;   // 6250 exact

    // ---- CSR build + sorted metadata stream ----
    zero_int_k<<<gblocks(NN), 256, 0, stream>>>(cur, NN);
    hist_k<<<gblocks(NE), 256, 0, stream>>>(dstp, cur);
    s1_k<<<SCAN_B, 256, 0, stream>>>(cur, offs, bsum);
    s2_k<<<1, 512, 0, stream>>>(bsum);
    s3_k<<<SCAN_B, 256, 0, stream>>>(offs, bsum);
    copyoff_k<<<SCAN_B, 256, 0, stream>>>(offs, cur);
    fill_k<<<gblocks(NE), 256, 0, stream>>>(dstp, srcp, (const float2*)attr, cur, emeta);
    dstbase_k<<<gblocks(NB), 256, 0, stream>>>(offs, dstbase);

    // ---- weight fragment packs ----
    castw_k<<<gblocks(9 * 2 * 64), 256, 0, stream>>>(W1, wtf1, 9);
    castw_k<<<gblocks(25 * 2 * 64), 256, 0, stream>>>(W2, wtf2, 25);

    // ---- layer 1 (ksize=3, K=9) ----
    castx_k<<<gblocks(NN * 4), 256, 0, stream>>>(x, xtf);
    ymm_k<9><<<gt, 64, 0, stream>>>((const short8v*)xtf, (const short8v*)wtf1, (uint2*)y);
    zero_k<<<gblocks((long)NN * DD), 256, 0, stream>>>(agg, (long)NN * DD);  // cur dead now
    edge_sr_k<3><<<NB, 256, 0, stream>>>(offs, dstbase, emeta, (const unsigned*)y, agg);
    fin1_k<<<gn, 256, 0, stream>>>(agg, offs, x, root1, bias1, xtf);  // h1 -> frags, agg -> 0

    // ---- layer 2 (ksize=5, K=25) ----
    ymm_k<25><<<gt, 64, 0, stream>>>((const short8v*)xtf, (const short8v*)wtf2, (uint2*)y);
    edge_sr_k<5><<<NB, 256, 0, stream>>>(offs, dstbase, emeta, (const unsigned*)y, agg);

    // ---- fused layer-2 finalize + MLP head ----
    finmlp_k<<<gn, 256, 0, stream>>>(agg, offs, xtf, root2, bias2,
                                     m1w, m1b, m2w, m2b, out);
}

// Round 14
// 629.092 us; speedup vs baseline: 3.8198x; 1.0656x over previous
//
#include <hip/hip_runtime.h>
#include <math.h>

#define NN 100000
#define NE 1600000
#define DD 32
#define CC 16
#define SCAN_B 391   // ceil(NN/256)
#define NB (NE / 8)  // 200000 edge blocks, exact

typedef unsigned short bf16_t;
typedef __attribute__((ext_vector_type(8))) short short8v;
typedef __attribute__((ext_vector_type(4))) float float4v;

static inline unsigned gblocks(long total) { return (unsigned)((total + 255) / 256); }

__device__ inline bf16_t f2bf(float f) {
    unsigned u = __float_as_uint(f);
    u += 0x7fffu + ((u >> 16) & 1u);
    return (bf16_t)(u >> 16);
}
__device__ inline float bf2f(bf16_t h) { return __uint_as_float(((unsigned)h) << 16); }
__device__ inline unsigned pk2(float a, float b) {
    return (unsigned)f2bf(a) | ((unsigned)f2bf(b) << 16);
}

__global__ void zero_k(float* p, long n) {
    long i = (long)blockIdx.x * 256 + threadIdx.x;
    if (i < n) p[i] = 0.f;
}
__global__ void zero_int_k(int* p, int n) {
    int i = blockIdx.x * 256 + threadIdx.x;
    if (i < n) p[i] = 0;
}

// ---------------- CSR build ----------------
__global__ void hist_k(const int* __restrict__ dst, int* __restrict__ cnt) {
    int e = blockIdx.x * 256 + threadIdx.x;
    if (e < NE) atomicAdd(&cnt[dst[e]], 1);
}
__global__ void s1_k(const int* __restrict__ cnt, int* __restrict__ offs,
                     int* __restrict__ bsum) {
    __shared__ int sm[256];
    int t = threadIdx.x, b = blockIdx.x;
    int g = b * 256 + t;
    int v = (g < NN) ? cnt[g] : 0;
    sm[t] = v;
    __syncthreads();
    for (int o = 1; o < 256; o <<= 1) {
        int u = (t >= o) ? sm[t - o] : 0;
        __syncthreads();
        sm[t] += u;
        __syncthreads();
    }
    if (g < NN) offs[g + 1] = sm[t];
    if (t == 255) bsum[b] = sm[255];
}
__global__ void s2_k(int* __restrict__ bsum) {
    __shared__ int sm[512];
    int t = threadIdx.x;
    int v = (t < SCAN_B) ? bsum[t] : 0;
    sm[t] = v;
    __syncthreads();
    for (int o = 1; o < 512; o <<= 1) {
        int u = (t >= o) ? sm[t - o] : 0;
        __syncthreads();
        sm[t] += u;
        __syncthreads();
    }
    if (t < SCAN_B) bsum[t] = sm[t] - v;  // exclusive
}
// fused: add block prefixes + init cur = final offs
__global__ void s3c_k(int* __restrict__ offs, const int* __restrict__ bsum,
                      int* __restrict__ cur) {
    int t = threadIdx.x, b = blockIdx.x;
    int g = b * 256 + t;
    if (g < NN) {
        int v = offs[g + 1] + bsum[b];
        offs[g + 1] = v;
        if (g + 1 < NN) cur[g + 1] = v;
    }
    if (g == 0) { offs[0] = 0; cur[0] = 0; }
}

// fill dst-sorted stream: emeta = {src[16:0] | dst[14:0]<<17,
//                                  q0[14:0] | q1[14:0]<<15 | dst[16:15]<<30}
__global__ void fill_k(const int* __restrict__ dst, const int* __restrict__ src,
                       const float2* __restrict__ attr, int* __restrict__ cur,
                       uint2* __restrict__ emeta) {
    int e = blockIdx.x * 256 + threadIdx.x;
    if (e < NE) {
        int d = dst[e];
        int pos = atomicAdd(&cur[d], 1);
        float2 uv = attr[e];
        unsigned q0 = (unsigned)(uv.x * 32767.f + 0.5f);
        unsigned q1 = (unsigned)(uv.y * 32767.f + 0.5f);
        uint2 m;
        m.x = (unsigned)src[e] | ((unsigned)(d & 0x7FFF) << 17);
        m.y = q0 | (q1 << 15) | ((unsigned)(d >> 15) << 30);
        emeta[pos] = m;
    }
}

// ---------------- MFMA y pipeline ----------------
__global__ void castx_k(const float* __restrict__ in, bf16_t* __restrict__ outf) {
    int tid = blockIdx.x * 256 + threadIdx.x;  // (n, q)
    if (tid >= NN * 4) return;
    int n = tid >> 2, q = tid & 3;
    const float4* ip = (const float4*)(in + (long)n * DD + q * 8);
    float4 v0 = ip[0], v1 = ip[1];
    int tile = n >> 4;
    int lane = (n & 15) + 16 * q;
    unsigned* op = (unsigned*)(outf + ((long)tile * 64 + lane) * 8);
    op[0] = pk2(v0.x, v0.y);
    op[1] = pk2(v0.z, v0.w);
    op[2] = pk2(v1.x, v1.y);
    op[3] = pk2(v1.z, v1.w);
}

// both weight packs in one launch
__global__ void castw2_k(const float* __restrict__ W1, const float* __restrict__ W2,
                         bf16_t* __restrict__ wtf1, bf16_t* __restrict__ wtf2) {
    int tid = blockIdx.x * 256 + threadIdx.x;
    const float* W; bf16_t* wtf; int loc;
    if (tid < 9 * 2 * 64) { W = W1; wtf = wtf1; loc = tid; }
    else if (tid < (9 + 25) * 2 * 64) { W = W2; wtf = wtf2; loc = tid - 9 * 2 * 64; }
    else return;
    int l = loc & 63;
    int half = (loc >> 6) & 1;
    int k = loc >> 7;
    int e = (l & 15) + 16 * half;
    int dbase = (l >> 4) * 8;
    bf16_t* op = wtf + (long)loc * 8;
#pragma unroll
    for (int r = 0; r < 8; ++r)
        op[r] = f2bf(W[(long)k * 1024 + (dbase + r) * DD + e]);
}

// y[n][k][d] = x[n,:] @ W[k]; direct register->global stores (r13-proven).
template<int K>
__global__ __launch_bounds__(64) void ymm_k(const short8v* __restrict__ xtf,
                                            const short8v* __restrict__ wtf,
                                            uint2* __restrict__ y) {
    const int l = threadIdx.x;
    const int tile = blockIdx.x;
    const int node = l & 15, g = l >> 4;

    short8v b = xtf[(long)tile * 64 + l];
    float4v zz = {0.f, 0.f, 0.f, 0.f};
    const long nb = ((long)tile * 16 + node) * K;

    for (int k = 0; k < K; ++k) {
        float4v d0 = __builtin_amdgcn_mfma_f32_16x16x32_bf16(wtf[(2 * k + 0) * 64 + l], b, zz, 0, 0, 0);
        float4v d1 = __builtin_amdgcn_mfma_f32_16x16x32_bf16(wtf[(2 * k + 1) * 64 + l], b, zz, 0, 0, 0);
        uint2 s0, s1;
        s0.x = pk2(d0[0], d0[1]); s0.y = pk2(d0[2], d0[3]);
        s1.x = pk2(d1[0], d1[1]); s1.y = pk2(d1[2], d1[3]);
        y[(nb + k) * 8 + g] = s0;
        y[(nb + k) * 8 + 4 + g] = s1;
    }
}

// ---------------- sorted edge phase (dst decoded from emeta) ----------------
template<int KS>
__global__ __launch_bounds__(256) void edge_sr_k(
        const uint2* __restrict__ emeta, const unsigned* __restrict__ yu,
        float* __restrict__ agg) {
    constexpr int K = KS * KS;
    __shared__ float smf[8][36];
    __shared__ int sdst[8];
    const int tid = threadIdx.x;
    const int lane = tid & 31, g = tid >> 5;
    const int al = lane & 15, half = lane >> 4;
    const int j = blockIdx.x * 8 + g;

    uint2 em = emeta[j];
    int s = (int)(em.x & 0x1FFFFu);
    int n = (int)((em.x >> 17) & 0x7FFFu) | ((int)((em.y >> 30) & 3u) << 15);
    float u0 = (float)(em.y & 0x7FFFu) * (1.f / 32767.f);
    float u1 = (float)((em.y >> 15) & 0x7FFFu) * (1.f / 32767.f);
    float v0 = u0 * (KS - 1), v1 = u1 * (KS - 1);
    int i0 = min((int)v0, KS - 2), i1 = min((int)v1, KS - 2);
    float f0 = v0 - (float)i0, f1 = v1 - (float)i1;

    float wh = half ? f0 : (1.f - f0);
    long base = ((long)s * K + i1 * KS + i0 + half) * 16 + al;
    unsigned uA = yu[base];             // plane i1, row (i0+half)
    unsigned uB = yu[base + KS * 16];   // plane i1+1
    float wA = wh * (1.f - f1), wB = wh * f1;
    float p0 = wA * bf2f((bf16_t)(uA & 0xffffu)) + wB * bf2f((bf16_t)(uB & 0xffffu));
    float p1 = wA * bf2f((bf16_t)(uA >> 16)) + wB * bf2f((bf16_t)(uB >> 16));
    p0 += __shfl_xor(p0, 16);
    p1 += __shfl_xor(p1, 16);

    if (half == 0) {
        smf[g][2 * al] = p0;
        smf[g][2 * al + 1] = p1;
    }
    if (lane == 0) sdst[g] = n;
    __syncthreads();

    bool leader = (g == 0) || (sdst[g - 1] != n);
    if (leader) {
        float acc = smf[g][lane];
#pragma unroll
        for (int gg = 1; gg < 8; ++gg) {
            int g2 = g + gg;
            if (g2 >= 8 || sdst[g2] != n) break;
            acc += smf[g2][lane];
        }
        atomicAdd(&agg[(long)n * DD + lane], acc);
    }
}

// finalize layer 1: h1 -> bf16 fragments; re-zero agg for layer 2
__global__ __launch_bounds__(256) void fin1_k(
        float* __restrict__ agg, const int* __restrict__ offs,
        const float* __restrict__ xin, const float* __restrict__ root,
        const float* __restrict__ bias, bf16_t* __restrict__ xtf) {
    const int lane = threadIdx.x & 31;
    const int grp = threadIdx.x >> 5;
    const int n = blockIdx.x * 8 + grp;
    if (n >= NN) return;
    int deg = offs[n + 1] - offs[n];
    float c = deg > 0 ? (float)deg : 1.f;
    float xv = xin[(long)n * DD + lane];
    float racc = 0.f;
#pragma unroll
    for (int d = 0; d < DD; ++d)
        racc = fmaf(__shfl(xv, d, 32), root[d * DD + lane], racc);
    float v = agg[(long)n * DD + lane] / c + racc + bias[lane];
    agg[(long)n * DD + lane] = 0.f;
    v = v > 0.f ? v : expm1f(v);
    xtf[((long)(n >> 4) * 64 + (n & 15) + 16 * (lane >> 3)) * 8 + (lane & 7)] = f2bf(v);
}

// fused: layer-2 finalize + 2-layer MLP head -> out
__global__ __launch_bounds__(256) void finmlp_k(
        const float* __restrict__ agg, const int* __restrict__ offs,
        const bf16_t* __restrict__ xtf, const float* __restrict__ root,
        const float* __restrict__ bias, const float* __restrict__ w1,
        const float* __restrict__ b1, const float* __restrict__ w2,
        const float* __restrict__ b2, float* __restrict__ out) {
    const int lane = threadIdx.x & 31;
    const int grp = threadIdx.x >> 5;
    const int n = blockIdx.x * 8 + grp;
    if (n >= NN) return;
    int deg = offs[n + 1] - offs[n];
    float c = deg > 0 ? (float)deg : 1.f;
    float h1 = bf2f(xtf[((long)(n >> 4) * 64 + (n & 15) + 16 * (lane >> 3)) * 8 + (lane & 7)]);
    float racc = 0.f;
#pragma unroll
    for (int d = 0; d < DD; ++d)
        racc = fmaf(__shfl(h1, d, 32), root[d * DD + lane], racc);
    float h2 = agg[(long)n * DD + lane] / c + racc + bias[lane];
    h2 = h2 > 0.f ? h2 : expm1f(h2);
    float t = b1[lane];
#pragma unroll
    for (int d = 0; d < DD; ++d)
        t = fmaf(__shfl(h2, d, 32), w1[d * DD + lane], t);
    t = fmaxf(t, 0.f);
    int cc = lane & (CC - 1);
    float o = 0.f;
#pragma unroll
    for (int d = 0; d < DD; ++d)
        o = fmaf(__shfl(t, d, 32), w2[d * CC + cc], o);
    o += b2[cc];
    o = fmaxf(o, 0.f);
    if (lane < CC) out[(long)n * CC + lane] = o;
}

extern "C" void kernel_launch(void* const* d_in, const int* in_sizes, int n_in,
                              void* d_out, int out_size, void* d_ws, size_t ws_size,
                              hipStream_t stream) {
    const float* x     = (const float*)d_in[0];
    const int*   ei    = (const int*)d_in[1];
    const float* attr  = (const float*)d_in[2];
    const float* W1    = (const float*)d_in[3];
    const float* root1 = (const float*)d_in[4];
    const float* bias1 = (const float*)d_in[5];
    const float* W2    = (const float*)d_in[6];
    const float* root2 = (const float*)d_in[7];
    const float* bias2 = (const float*)d_in[8];
    const float* m1w   = (const float*)d_in[9];
    const float* m1b   = (const float*)d_in[10];
    const float* m2w   = (const float*)d_in[11];
    const float* m2b   = (const float*)d_in[12];
    float* out = (float*)d_out;

    const int* srcp = ei;
    const int* dstp = ei + NE;

    // ws: offs(NN+8) | emeta(NE uint2) | xtf(NN*32 bf16) | wtf1 | wtf2
    //     | y(NN*25*32 bf16) | agg(NN*32 f32)   ~192.6 MB
    // cur/bsum alias agg during the CSR phase (agg zeroed after fill).
    int* offs = (int*)d_ws;
    uint2* emeta = (uint2*)(offs + NN + 8);
    bf16_t* xtf = (bf16_t*)(emeta + NE);
    bf16_t* wtf1 = xtf + (size_t)NN * DD;
    bf16_t* wtf2 = wtf1 + 9 * 2 * 64 * 8;
    bf16_t* y = wtf2 + 25 * 2 * 64 * 8;
    float* agg = (float*)(y + (size_t)NN * 25 * DD);
    int* cur  = (int*)agg;
    int* bsum = (int*)agg + NN;

    const unsigned gn = (NN + 7) / 8;
    const unsigned gt = NN / 16;   // 6250 exact

    // ---- CSR build + sorted packed metadata ----
    zero_int_k<<<gblocks(NN), 256, 0, stream>>>(cur, NN);
    hist_k<<<gblocks(NE), 256, 0, stream>>>(dstp, cur);
    s1_k<<<SCAN_B, 256, 0, stream>>>(cur, offs, bsum);
    s2_k<<<1, 512, 0, stream>>>(bsum);
    s3c_k<<<SCAN_B, 256, 0, stream>>>(offs, bsum, cur);
    fill_k<<<gblocks(NE), 256, 0, stream>>>(dstp, srcp, (const float2*)attr, cur, emeta);

    // ---- weight packs + input cast ----
    castw2_k<<<gblocks((9 + 25) * 2 * 64), 256, 0, stream>>>(W1, W2, wtf1, wtf2);
    castx_k<<<gblocks(NN * 4), 256, 0, stream>>>(x, xtf);

    // ---- layer 1 (ksize=3, K=9) ----
    ymm_k<9><<<gt, 64, 0, stream>>>((const short8v*)xtf, (const short8v*)wtf1, (uint2*)y);
    zero_k<<<gblocks((long)NN * DD), 256, 0, stream>>>(agg, (long)NN * DD);  // cur dead now
    edge_sr_k<3><<<NB, 256, 0, stream>>>(emeta, (const unsigned*)y, agg);
    fin1_k<<<gn, 256, 0, stream>>>(agg, offs, x, root1, bias1, xtf);

    // ---- layer 2 (ksize=5, K=25) ----
    ymm_k<25><<<gt, 64, 0, stream>>>((const short8v*)xtf, (const short8v*)wtf2, (uint2*)y);
    edge_sr_k<5><<<NB, 256, 0, stream>>>(emeta, (const unsigned*)y, agg);

    // ---- fused layer-2 finalize + MLP head ----
    finmlp_k<<<gn, 256, 0, stream>>>(agg, offs, xtf, root2, bias2,
                                     m1w, m1b, m2w, m2b, out);
}